// Round 13
// baseline (251.304 us; speedup 1.0000x reference)
//
#include <hip/hip_runtime.h>

typedef __bf16 bf16x8 __attribute__((ext_vector_type(8)));
typedef float f32x4 __attribute__((ext_vector_type(4)));
typedef float f32x16 __attribute__((ext_vector_type(16)));
typedef unsigned short u16x4 __attribute__((ext_vector_type(4)));
typedef unsigned int u32x4 __attribute__((ext_vector_type(4)));

#define L2E 1.44269504088896340736f

__device__ __forceinline__ f32x4 mfma16(bf16x8 a, bf16x8 b, f32x4 c) {
  return __builtin_amdgcn_mfma_f32_16x16x32_bf16(a, b, c, 0, 0, 0);
}
__device__ __forceinline__ f32x16 mfma32(bf16x8 a, bf16x8 b, f32x16 c) {
  return __builtin_amdgcn_mfma_f32_32x32x16_bf16(a, b, c, 0, 0, 0);
}

// global -> LDS direct copy, 16B per lane. LDS dest must be wave-uniform;
// lane l lands at dest + l*16 bytes.
__device__ __forceinline__ void async16(const __bf16* g, __bf16* l) {
  __builtin_amdgcn_global_load_lds(
      (const __attribute__((address_space(1))) void*)g,
      (__attribute__((address_space(3))) void*)l, 16, 0, 0);
}

// pack two f32 -> one u32 of 2 bf16 (lo=x, hi=y)
__device__ __forceinline__ unsigned pk(float x, float y) {
  unsigned short lo = __builtin_bit_cast(unsigned short, (__bf16)x);
  unsigned short hi = __builtin_bit_cast(unsigned short, (__bf16)y);
  return ((unsigned)hi << 16) | (unsigned)lo;
}

// ---------------- fp32 -> bf16 conversion: x + five weights, ONE launch --
__global__ __launch_bounds__(256) void cvt_all(
    const float* __restrict__ x, const float* __restrict__ wqd,
    const float* __restrict__ wkvd, const float* __restrict__ wqup,
    const float* __restrict__ wkup, const float* __restrict__ wvup,
    __bf16* __restrict__ dx, __bf16* __restrict__ dqkv,
    __bf16* __restrict__ dqu, __bf16* __restrict__ dku,
    __bf16* __restrict__ dvu) {
  int bx = blockIdx.x;
  const float* s;
  __bf16* d;
  int off;
  if (bx < 8192)       { s = x;    d = dx;                off = bx; }
  else if (bx < 10240) { s = wqd;  d = dqkv;              off = bx - 8192; }
  else if (bx < 11264) { s = wkvd; d = dqkv + 1024 * 2048; off = bx - 10240; }
  else if (bx < 13312) { s = wqup; d = dqu;               off = bx - 11264; }
  else if (bx < 14336) { s = wkup; d = dku;               off = bx - 13312; }
  else                 { s = wvup; d = dvu;               off = bx - 14336; }
  long i = (long)off * 1024 + threadIdx.x * 4;
  f32x4 v = *(const f32x4*)(s + i);
  u16x4 o;
#pragma unroll
  for (int j = 0; j < 4; j++) o[j] = __builtin_bit_cast(unsigned short, (__bf16)v[j]);
  *(u16x4*)((unsigned short*)d + i) = o;
}

__global__ __launch_bounds__(256) void cvt_bf16(const float* __restrict__ s,
                                                __bf16* __restrict__ d) {
  long i = (long)(blockIdx.x * 256 + threadIdx.x) * 4;
  f32x4 v = *(const f32x4*)(s + i);
  u16x4 o;
#pragma unroll
  for (int j = 0; j < 4; j++) o[j] = __builtin_bit_cast(unsigned short, (__bf16)v[j]);
  *(u16x4*)((unsigned short*)d + i) = o;
}

// ---------------- bf16 GEMM body: C[M,N] = A[M,K] @ Bt[N,K]^T ------------
template <int OUTF32>
__device__ __forceinline__ void gemm_body(
    __bf16* As, __bf16* Bs, const __bf16* __restrict__ A,
    const __bf16* __restrict__ Bt, void* __restrict__ Cout,
    const float* __restrict__ bias, int lda, int ldb, int ldc, int N, int K,
    float scale, int bx, int by, int permn) {
  const int tid = threadIdx.x;
  const int wid = tid >> 6, lane = tid & 63;
  const int lrow = lane & 15, lkhi = lane >> 4;
  const int row0 = bx * 128, col0 = by * 128;
  const int wr = (wid >> 1) * 64, wc = (wid & 1) * 64;

  const int trow = tid >> 2;                       // tile row within issue
  const int scol = 8 * ((tid & 3) ^ (trow & 3));   // pre-swizzled source col
  const __bf16* pA0 = A + (size_t)(row0 + trow) * lda + scol;
  const __bf16* pA1 = pA0 + (size_t)64 * lda;
  const __bf16* pB0 = Bt + (size_t)(col0 + trow) * ldb + scol;
  const __bf16* pB1 = pB0 + (size_t)64 * ldb;
  __bf16* lA0 = As + wid * 512;
  __bf16* lA1 = As + 2048 + wid * 512;
  __bf16* lB0 = Bs + wid * 512;
  __bf16* lB1 = Bs + 2048 + wid * 512;

  int aoff[4], boff[4];
#pragma unroll
  for (int i = 0; i < 4; i++) {
    int rr = wr + i * 16 + lrow;
    aoff[i] = rr * 32 + 8 * (lkhi ^ (rr & 3));
    rr = wc + i * 16 + lrow;
    boff[i] = rr * 32 + 8 * (lkhi ^ (rr & 3));
  }

  f32x4 acc[4][4] = {};
  for (int k0 = 0; k0 < K; k0 += 32) {
    __syncthreads();
    async16(pA0, lA0);
    async16(pA1, lA1);
    async16(pB0, lB0);
    async16(pB1, lB1);
    pA0 += 32; pA1 += 32; pB0 += 32; pB1 += 32;
    __syncthreads();
    bf16x8 af[4], bv[4];
#pragma unroll
    for (int mi = 0; mi < 4; mi++) af[mi] = *(const bf16x8*)(As + aoff[mi]);
#pragma unroll
    for (int ni = 0; ni < 4; ni++) bv[ni] = *(const bf16x8*)(Bs + boff[ni]);
#pragma unroll
    for (int mi = 0; mi < 4; mi++)
#pragma unroll
      for (int ni = 0; ni < 4; ni++)
        acc[mi][ni] = mfma16(af[mi], bv[ni], acc[mi][ni]);
  }

  const int orow = row0 + wr + lkhi * 4;
  const int prow = permn ? ((lrow & 3) | ((lrow & 4) << 1) | ((lrow & 8) >> 1))
                         : lrow;
  const int ocol = col0 + wc + prow;
#pragma unroll
  for (int mi = 0; mi < 4; mi++)
#pragma unroll
    for (int ni = 0; ni < 4; ni++)
#pragma unroll
      for (int r = 0; r < 4; r++) {
        size_t idx = (size_t)(orow + mi * 16 + r) * ldc + (ocol + ni * 16);
        float v = acc[mi][ni][r] * scale;
        if (OUTF32)
          ((float*)Cout)[idx] = v + bias[ocol + ni * 16];
        else
          ((__bf16*)Cout)[idx] = (__bf16)v;
      }
}

template <int OUTF32, int PERMN = 0>
__global__ __launch_bounds__(256, 3) void gemm_bt(
    const __bf16* __restrict__ A, const __bf16* __restrict__ Bt,
    void* __restrict__ Cout, const float* __restrict__ bias,
    int lda, int ldb, int ldc, int N, int K, float scale) {
  __shared__ __align__(16) __bf16 As[4096];
  __shared__ __align__(16) __bf16 Bs[4096];
  gemm_body<OUTF32>(As, Bs, A, Bt, Cout, bias, lda, ldb, ldc, N, K, scale,
                    blockIdx.x, blockIdx.y, PERMN);
}

// merged middle GEMMs: Q-up (512 blocks) + K-up (512) + V^T-up (512).
__global__ __launch_bounds__(256, 3) void gemm_mid(
    const __bf16* __restrict__ qlat, const __bf16* __restrict__ ckv,
    const __bf16* __restrict__ wqu, const __bf16* __restrict__ wku,
    const __bf16* __restrict__ wvu, __bf16* __restrict__ qf,
    __bf16* __restrict__ kf, __bf16* __restrict__ vt) {
  __shared__ __align__(16) __bf16 As[4096];
  __shared__ __align__(16) __bf16 Bs[4096];
  int bid = (int)blockIdx.x;
  if (bid < 512) {
    gemm_body<0>(As, Bs, qlat, wqu, qf, nullptr, 1536, 1024, 2048, 2048, 1024,
                 0.12752039360437355f, bid & 31, bid >> 5, 0);
  } else if (bid < 1024) {
    bid -= 512;
    gemm_body<0>(As, Bs, ckv, wku, kf, nullptr, 1536, 512, 2048, 2048, 512,
                 1.0f, bid & 31, bid >> 5, 0);
  } else {
    bid -= 1024;
    gemm_body<0>(As, Bs, wvu, ckv, vt, nullptr, 512, 1536, 4096, 4096, 512,
                 1.0f, bid & 15, bid >> 4, 1);
  }
}

// ---------------- causal flash attention (split-KV + tile pipeline) ------
// R12 base + R13: QK(t+1) hoisted into region t -- its MFMA/ds_read work is
// independent of tile t's softmax/PV, so it fills tile t's VALU stalls.
// Buffering: K staged 2-ahead in a dbuf (K[t] dies a region before V[t]);
// V staged 1-ahead in a dbuf. All same-region buffer accesses touch
// disjoint parities; extra prologue barrier isolates QK(0) from the first
// restage of Kbuf0.
__global__ __launch_bounds__(512, 1) void mla_attn(
    const __bf16* __restrict__ Qf, const __bf16* __restrict__ Kf,
    const __bf16* __restrict__ Vt, __bf16* __restrict__ ctx) {
  __shared__ __align__(16) __bf16 SM[2][32768];  // per quad: K dbuf | V dbuf
  __shared__ float MLm[128], MLl[128];

  const int bid = (int)blockIdx.x;
  const int qt = 15 - (bid >> 5);    // big first (LPT); bid%8=bh%8 (XCD)
  const int bh = bid & 31;
  const int h = bh >> 1, b = bh & 1;
  const int tid = threadIdx.x;
  const int half = tid >> 8;          // quad index
  const int htid = tid & 255;
  const int wid4 = htid >> 6;         // wave within quad
  const int lane = tid & 63;
  const int l31 = lane & 31;
  const bool hh = (lane & 32) != 0;

  __bf16* Ks = &SM[half][0];          // [2][64*128], swz (row&15)
  __bf16* Vs = &SM[half][16384];      // [2][128*64], swz (row&7)

  const __bf16* Kbh = Kf + (size_t)b * 2048 * 2048 + h * 128;
  const __bf16* Vbh = Vt + (size_t)h * 128 * 4096 + b * 2048;

  auto stageK = [&](int k0, int buf) {
#pragma unroll
    for (int i = 0; i < 4; i++) {
      int e = i * 2048 + htid * 8;
      int krow = e >> 7;
      int kcol = (e & 127) ^ (8 * (krow & 15));
      async16(Kbh + (size_t)(k0 + krow) * 2048 + kcol,
              Ks + buf * 8192 + i * 2048 + wid4 * 512);
    }
  };
  auto stageV = [&](int k0, int buf) {
#pragma unroll
    for (int i = 0; i < 4; i++) {
      int e = i * 2048 + htid * 8;
      int vrow = e >> 6;
      int vcol = (e & 63) ^ (8 * (vrow & 7));
      async16(Vbh + (size_t)vrow * 4096 + k0 + vcol,
              Vs + buf * 8192 + i * 2048 + wid4 * 512);
    }
  };

  const int q0 = qt * 128;
  const int ntile = qt + 1;           // tiles per quad
  const int kbase = half * ntile;     // this quad's first kv tile
  const int q = q0 + wid4 * 32 + l31; // this lane's q-row

  // Q fragments (B-operand layout: col=q=lane&31, k-rows (lane>>5)*8+j)
  bf16x8 qb[8];
  const __bf16* qrow =
      Qf + (size_t)(b * 2048 + q) * 2048 + h * 128 + (hh ? 8 : 0);
#pragma unroll
  for (int ds = 0; ds < 8; ds++) qb[ds] = *(const bf16x8*)(qrow + ds * 16);

  // S^T = K Q^T for one 64-key tile from Kbuf[buf]; 4 independent chains.
  auto computeQK = [&](int buf, f32x16* s) {
    f32x16 sa0 = {}, sa1 = {}, sb0 = {}, sb1 = {};
    const __bf16* kp = Ks + buf * 8192;
    __builtin_amdgcn_s_setprio(1);
#pragma unroll
    for (int ds = 0; ds < 4; ds++) {
      int row0_ = l31, row1_ = 32 + l31;
      int c0 = (ds * 16 + (hh ? 8 : 0)) ^ (8 * (row0_ & 15));
      int c1 = (ds * 16 + (hh ? 8 : 0)) ^ (8 * (row1_ & 15));
      bf16x8 k0f = *(const bf16x8*)(kp + row0_ * 128 + c0);
      bf16x8 k1f = *(const bf16x8*)(kp + row1_ * 128 + c1);
      sa0 = mfma32(k0f, qb[ds], sa0);
      sa1 = mfma32(k1f, qb[ds], sa1);
    }
#pragma unroll
    for (int ds = 4; ds < 8; ds++) {
      int row0_ = l31, row1_ = 32 + l31;
      int c0 = (ds * 16 + (hh ? 8 : 0)) ^ (8 * (row0_ & 15));
      int c1 = (ds * 16 + (hh ? 8 : 0)) ^ (8 * (row1_ & 15));
      bf16x8 k0f = *(const bf16x8*)(kp + row0_ * 128 + c0);
      bf16x8 k1f = *(const bf16x8*)(kp + row1_ * 128 + c1);
      sb0 = mfma32(k0f, qb[ds], sb0);
      sb1 = mfma32(k1f, qb[ds], sb1);
    }
    __builtin_amdgcn_s_setprio(0);
    s[0] = sa0 + sb0;
    s[1] = sa1 + sb1;
  };

  f32x16 o[4] = {};
  float mrow = 0.f, lsum = 0.f;  // finite init: speculative exp stays in range

  // prologue: K0,V0,K1 staged; QK(0) isolated by its own barrier
  stageK(kbase * 64, 0);
  stageV(kbase * 64, 0);
  if (ntile > 1) stageK(kbase * 64 + 64, 1);
  __syncthreads();  // P1: K0,V0,K1 in LDS
  f32x16 scur[2];
  computeQK(0, scur);
  __syncthreads();  // P2: QK(0)'s LDS reads complete before Kbuf0 restage

  for (int t = 0; t < ntile; t++) {
    const int kb = kbase + t;
    const int k0 = kb * 64;

    // stage ahead: K two tiles out (into the K buffer freed last region),
    // V one tile out (disjoint parity from this region's PV reads).
    if (t + 2 < ntile) stageK(k0 + 128, t & 1);
    if (t + 1 < ntile) stageV(k0 + 64, (t + 1) & 1);

    // QK(t+1): independent MFMA work to overlap tile t's softmax VALU.
    f32x16 snext[2];
    if (t + 1 < ntile) computeQK((t + 1) & 1, snext);

    // causal mask (global kb) -- true (unpermuted) key indices
    if (kb >= 2 * qt) {
#pragma unroll
      for (int kt = 0; kt < 2; kt++)
#pragma unroll
        for (int r = 0; r < 16; r++) {
          int key = k0 + kt * 32 + (r & 3) + 8 * (r >> 2) + (hh ? 4 : 0);
          if (key > q) scur[kt][r] = -1e30f;
        }
    }

    // side-chain: block max (pairwise tree) -- NOT on the exp/PV path
    float t16[16];
#pragma unroll
    for (int r = 0; r < 16; r++) t16[r] = fmaxf(scur[0][r], scur[1][r]);
#pragma unroll
    for (int s = 8; s; s >>= 1)
#pragma unroll
      for (int r = 0; r < s; r++) t16[r] = fmaxf(t16[r], t16[r + s]);
    float pm = fmaxf(t16[0], __shfl_xor(t16[0], 32));

    // critical path: speculative exp with OLD base (defer-max algebra)
    float ps0 = 0.f, ps1 = 0.f, ps2 = 0.f, ps3 = 0.f;
#pragma unroll
    for (int kt = 0; kt < 2; kt++)
#pragma unroll
      for (int r = 0; r < 16; r += 4) {
        float a0 = __builtin_amdgcn_exp2f(scur[kt][r + 0] - mrow);
        float a1 = __builtin_amdgcn_exp2f(scur[kt][r + 1] - mrow);
        float a2 = __builtin_amdgcn_exp2f(scur[kt][r + 2] - mrow);
        float a3 = __builtin_amdgcn_exp2f(scur[kt][r + 3] - mrow);
        scur[kt][r + 0] = a0; scur[kt][r + 1] = a1;
        scur[kt][r + 2] = a2; scur[kt][r + 3] = a3;
        ps0 += a0; ps1 += a1; ps2 += a2; ps3 += a3;
      }

    // O += P V : A-fragment = DIRECT pack of scur (V key-permuted).
    __builtin_amdgcn_s_setprio(1);
#pragma unroll
    for (int s = 0; s < 4; s++) {
      const int kt = s >> 1, r8 = (s & 1) * 8;
      u32x4 wv;
      wv.x = pk(scur[kt][r8 + 0], scur[kt][r8 + 1]);
      wv.y = pk(scur[kt][r8 + 2], scur[kt][r8 + 3]);
      wv.z = pk(scur[kt][r8 + 4], scur[kt][r8 + 5]);
      wv.w = pk(scur[kt][r8 + 6], scur[kt][r8 + 7]);
      bf16x8 pa = __builtin_bit_cast(bf16x8, wv);
#pragma unroll
      for (int dt = 0; dt < 4; dt++) {
        int vrow = dt * 32 + l31;
        int vcol = (s * 16 + (hh ? 8 : 0)) ^ (8 * (vrow & 7));
        bf16x8 vf = *(const bf16x8*)(Vs + (t & 1) * 8192 + vrow * 64 + vcol);
        o[dt] = mfma32(pa, vf, o[dt]);
      }
    }
    __builtin_amdgcn_s_setprio(0);

    float ps = (ps0 + ps1) + (ps2 + ps3);
    ps += __shfl_xor(ps, 32);
    lsum += ps;

    // deferred rescale AFTER PV (rare): keeps the O/l invariant exactly.
    if (__any(pm > mrow + 8.f)) {
      float mn = fmaxf(mrow, pm);
      float sf = __builtin_amdgcn_exp2f(mrow - mn);
      mrow = mn;
      lsum *= sf;
#pragma unroll
      for (int r = 0; r < 16; r++) {
        int ql = (r & 3) + 8 * (r >> 2) + (hh ? 4 : 0);
        float sr = __shfl(sf, ql);
#pragma unroll
        for (int dt = 0; dt < 4; dt++) o[dt][r] *= sr;
      }
    }

    __syncthreads();  // B_t: drains stages; orders buffer reuse
    if (t + 1 < ntile) { scur[0] = snext[0]; scur[1] = snext[1]; }
  }

  // ---- 2-way combine: quad1 -> LDS, quad0 merges (exact fp32) ----
  float* om = (float*)&SM[1][0];  // 16384 f32 = 64KB, [wave4][dt][lane][r]
  if (half == 1) {
#pragma unroll
    for (int dt = 0; dt < 4; dt++) {
      int base = ((wid4 * 4 + dt) * 64 + lane) * 16;
#pragma unroll
      for (int r = 0; r < 16; r++) om[base + r] = o[dt][r];
    }
    if (!hh) { MLm[wid4 * 32 + l31] = mrow; MLl[wid4 * 32 + l31] = lsum; }
  }
  __syncthreads();
  if (half == 0) {
#pragma unroll
    for (int r = 0; r < 16; r++) {
      int ql = (r & 3) + 8 * (r >> 2) + (hh ? 4 : 0);
      float m0r = __shfl(mrow, ql);
      float l0r = __shfl(lsum, ql);
      float m1r = MLm[wid4 * 32 + ql];
      float l1r = MLl[wid4 * 32 + ql];
      float M = fmaxf(m0r, m1r);
      float w0 = __builtin_amdgcn_exp2f(m0r - M);
      float w1 = __builtin_amdgcn_exp2f(m1r - M);
      float inv = 1.f / (l0r * w0 + l1r * w1);
      size_t rowi = (size_t)(b * 2048 + q0 + wid4 * 32 + ql) * 2048 + h * 128;
#pragma unroll
      for (int dt = 0; dt < 4; dt++) {
        float o1v = om[((wid4 * 4 + dt) * 64 + lane) * 16 + r];
        ctx[rowi + dt * 32 + l31] = (__bf16)((o[dt][r] * w0 + o1v * w1) * inv);
      }
    }
  }
}

// ---------------- launch ----------------
extern "C" void kernel_launch(void* const* d_in, const int* in_sizes, int n_in,
                              void* d_out, int out_size, void* d_ws, size_t ws_size,
                              hipStream_t stream) {
  (void)in_sizes; (void)n_in; (void)out_size; (void)ws_size;
  const float* x    = (const float*)d_in[0];
  const float* wqd  = (const float*)d_in[1];
  const float* wkvd = (const float*)d_in[2];
  const float* wqup = (const float*)d_in[3];
  const float* wkup = (const float*)d_in[4];
  const float* wvup = (const float*)d_in[5];
  const float* wo   = (const float*)d_in[6];
  const float* bo   = (const float*)d_in[7];

  char* ws = (char*)d_ws;
  const size_t MB = 1024 * 1024;
  __bf16* x_bf     = (__bf16*)(ws + 0);        // 16MB; reused as ctx
  __bf16* q_full   = (__bf16*)(ws + 16 * MB);  // 16MB
  __bf16* k_full   = (__bf16*)(ws + 32 * MB);  // 16MB
  __bf16* vt       = (__bf16*)(ws + 48 * MB);  // 16MB (key axis pi-permuted)
  __bf16* qkv_lat  = (__bf16*)(ws + 64 * MB);  // 12MB [4096,1536]; reused wo_bf
  __bf16* wqkvd_bf = (__bf16*)(ws + 76 * MB);  // 6MB  [1536,2048] fused
  __bf16* wqup_bf  = (__bf16*)(ws + 82 * MB);  // 4MB
  __bf16* wkup_bf  = (__bf16*)(ws + 86 * MB);  // 2MB
  __bf16* wvup_bf  = (__bf16*)(ws + 88 * MB);  // 2MB -> total 90MB
  __bf16* ctx   = x_bf;      // x_bf dead after fused down-proj
  __bf16* wo_bf = qkv_lat;   // qkv_lat dead after gemm_mid

  // one launch: x + all five projection weights
  cvt_all<<<15360, 256, 0, stream>>>(x, wqd, wkvd, wqup, wkup, wvup, x_bf,
                                     wqkvd_bf, wqup_bf, wkup_bf, wvup_bf);

  dim3 blk(256);
  // [Q_lat | C_kv] = x @ [Wq_down; Wkv_down]^T   (fused, N=1536)
  gemm_bt<0><<<dim3(32, 12), blk, 0, stream>>>(x_bf, wqkvd_bf, qkv_lat, nullptr,
                                               2048, 2048, 1536, 1536, 2048, 1.0f);
  // Q-up + K-up + V^T-up in ONE launch (1536 blocks, 3/CU)
  gemm_mid<<<1536, blk, 0, stream>>>(qkv_lat, qkv_lat + 1024, wqup_bf, wkup_bf,
                                     wvup_bf, q_full, k_full, vt);
  cvt_bf16<<<4096, 256, 0, stream>>>(wo, wo_bf);  // qkv_lat free after mid
  // ctx = causal_attention(Q, K, V): 512 blocks x 512 thr, split-KV in-block
  mla_attn<<<512, 512, 0, stream>>>(q_full, k_full, vt, ctx);
  // out = ctx @ Wo^T + bo  (fp32)
  gemm_bt<1><<<dim3(32, 16), blk, 0, stream>>>(ctx, wo_bf, (float*)d_out, bo,
                                               2048, 2048, 2048, 2048, 2048, 1.0f);
}

// Round 14
// 196.914 us; speedup vs baseline: 1.2762x; 1.2762x over previous
//
#include <hip/hip_runtime.h>

typedef __bf16 bf16x8 __attribute__((ext_vector_type(8)));
typedef float f32x4 __attribute__((ext_vector_type(4)));
typedef float f32x16 __attribute__((ext_vector_type(16)));
typedef unsigned short u16x4 __attribute__((ext_vector_type(4)));
typedef unsigned int u32x4 __attribute__((ext_vector_type(4)));

#define L2E 1.44269504088896340736f

__device__ __forceinline__ f32x4 mfma16(bf16x8 a, bf16x8 b, f32x4 c) {
  return __builtin_amdgcn_mfma_f32_16x16x32_bf16(a, b, c, 0, 0, 0);
}
__device__ __forceinline__ f32x16 mfma32(bf16x8 a, bf16x8 b, f32x16 c) {
  return __builtin_amdgcn_mfma_f32_32x32x16_bf16(a, b, c, 0, 0, 0);
}

// global -> LDS direct copy, 16B per lane. LDS dest must be wave-uniform;
// lane l lands at dest + l*16 bytes.
__device__ __forceinline__ void async16(const __bf16* g, __bf16* l) {
  __builtin_amdgcn_global_load_lds(
      (const __attribute__((address_space(1))) void*)g,
      (__attribute__((address_space(3))) void*)l, 16, 0, 0);
}

// pack two f32 -> one u32 of 2 bf16 (lo=x, hi=y)
__device__ __forceinline__ unsigned pk(float x, float y) {
  unsigned short lo = __builtin_bit_cast(unsigned short, (__bf16)x);
  unsigned short hi = __builtin_bit_cast(unsigned short, (__bf16)y);
  return ((unsigned)hi << 16) | (unsigned)lo;
}

// ---------------- fp32 -> bf16 conversion: x + five weights, ONE launch --
__global__ __launch_bounds__(256) void cvt_all(
    const float* __restrict__ x, const float* __restrict__ wqd,
    const float* __restrict__ wkvd, const float* __restrict__ wqup,
    const float* __restrict__ wkup, const float* __restrict__ wvup,
    __bf16* __restrict__ dx, __bf16* __restrict__ dqkv,
    __bf16* __restrict__ dqu, __bf16* __restrict__ dku,
    __bf16* __restrict__ dvu) {
  int bx = blockIdx.x;
  const float* s;
  __bf16* d;
  int off;
  if (bx < 8192)       { s = x;    d = dx;                off = bx; }
  else if (bx < 10240) { s = wqd;  d = dqkv;              off = bx - 8192; }
  else if (bx < 11264) { s = wkvd; d = dqkv + 1024 * 2048; off = bx - 10240; }
  else if (bx < 13312) { s = wqup; d = dqu;               off = bx - 11264; }
  else if (bx < 14336) { s = wkup; d = dku;               off = bx - 13312; }
  else                 { s = wvup; d = dvu;               off = bx - 14336; }
  long i = (long)off * 1024 + threadIdx.x * 4;
  f32x4 v = *(const f32x4*)(s + i);
  u16x4 o;
#pragma unroll
  for (int j = 0; j < 4; j++) o[j] = __builtin_bit_cast(unsigned short, (__bf16)v[j]);
  *(u16x4*)((unsigned short*)d + i) = o;
}

__global__ __launch_bounds__(256) void cvt_bf16(const float* __restrict__ s,
                                                __bf16* __restrict__ d) {
  long i = (long)(blockIdx.x * 256 + threadIdx.x) * 4;
  f32x4 v = *(const f32x4*)(s + i);
  u16x4 o;
#pragma unroll
  for (int j = 0; j < 4; j++) o[j] = __builtin_bit_cast(unsigned short, (__bf16)v[j]);
  *(u16x4*)((unsigned short*)d + i) = o;
}

// ---------------- bf16 GEMM body: C[M,N] = A[M,K] @ Bt[N,K]^T ------------
// 128x128 tile, BK=64 (half the barrier drains of BK=32), 4 waves,
// 16x16x32 MFMA x2 per staged tile, global_load_lds staging.
// LDS swizzled: tile[row][c] at LDS[row*64 + (c ^ 8*(row&7))], rows 128B.
// permn!=0: output column c stored at (c&~15)|bitswap23(c&15) (V key perm).
template <int OUTF32>
__device__ __forceinline__ void gemm_body(
    __bf16* As, __bf16* Bs, const __bf16* __restrict__ A,
    const __bf16* __restrict__ Bt, void* __restrict__ Cout,
    const float* __restrict__ bias, int lda, int ldb, int ldc, int N, int K,
    float scale, int bx, int by, int permn) {
  const int tid = threadIdx.x;
  const int wid = tid >> 6, lane = tid & 63;
  const int lrow = lane & 15, lkhi = lane >> 4;
  const int row0 = bx * 128, col0 = by * 128;
  const int wr = (wid >> 1) * 64, wc = (wid & 1) * 64;

  // staging: pass p covers rows 32p..32p+31; thread = row tid>>3, blk tid&7.
  // source col pre-swizzled (row-invariant across passes since 32%8==0).
  const int trow = tid >> 3;
  const int scol = 8 * ((tid & 7) ^ (trow & 7));
  const __bf16* pA = A + (size_t)(row0 + trow) * lda + scol;
  const __bf16* pB = Bt + (size_t)(col0 + trow) * ldb + scol;

  f32x4 acc[4][4] = {};
  for (int k0 = 0; k0 < K; k0 += 64) {
    __syncthreads();
#pragma unroll
    for (int p = 0; p < 4; p++)
      async16(pA + (size_t)(32 * p) * lda, As + p * 2048 + wid * 512);
#pragma unroll
    for (int p = 0; p < 4; p++)
      async16(pB + (size_t)(32 * p) * ldb, Bs + p * 2048 + wid * 512);
    pA += 64; pB += 64;
    __syncthreads();
#pragma unroll
    for (int kk = 0; kk < 2; kk++) {
      bf16x8 af[4], bv[4];
#pragma unroll
      for (int mi = 0; mi < 4; mi++) {
        int rr = wr + mi * 16 + lrow;
        af[mi] = *(const bf16x8*)(As + rr * 64 +
                                  ((kk * 32 + lkhi * 8) ^ (8 * (rr & 7))));
      }
#pragma unroll
      for (int ni = 0; ni < 4; ni++) {
        int rr = wc + ni * 16 + lrow;
        bv[ni] = *(const bf16x8*)(Bs + rr * 64 +
                                  ((kk * 32 + lkhi * 8) ^ (8 * (rr & 7))));
      }
#pragma unroll
      for (int mi = 0; mi < 4; mi++)
#pragma unroll
        for (int ni = 0; ni < 4; ni++)
          acc[mi][ni] = mfma16(af[mi], bv[ni], acc[mi][ni]);
    }
  }

  const int orow = row0 + wr + lkhi * 4;
  const int prow = permn ? ((lrow & 3) | ((lrow & 4) << 1) | ((lrow & 8) >> 1))
                         : lrow;
  const int ocol = col0 + wc + prow;
#pragma unroll
  for (int mi = 0; mi < 4; mi++)
#pragma unroll
    for (int ni = 0; ni < 4; ni++)
#pragma unroll
      for (int r = 0; r < 4; r++) {
        size_t idx = (size_t)(orow + mi * 16 + r) * ldc + (ocol + ni * 16);
        float v = acc[mi][ni][r] * scale;
        if (OUTF32)
          ((float*)Cout)[idx] = v + bias[ocol + ni * 16];
        else
          ((__bf16*)Cout)[idx] = (__bf16)v;
      }
}

template <int OUTF32, int PERMN = 0>
__global__ __launch_bounds__(256, 3) void gemm_bt(
    const __bf16* __restrict__ A, const __bf16* __restrict__ Bt,
    void* __restrict__ Cout, const float* __restrict__ bias,
    int lda, int ldb, int ldc, int N, int K, float scale) {
  __shared__ __align__(16) __bf16 As[8192];
  __shared__ __align__(16) __bf16 Bs[8192];
  gemm_body<OUTF32>(As, Bs, A, Bt, Cout, bias, lda, ldb, ldc, N, K, scale,
                    blockIdx.x, blockIdx.y, PERMN);
}

// merged middle GEMMs: Q-up (512 blocks) + K-up (512) + V^T-up (512).
__global__ __launch_bounds__(256, 3) void gemm_mid(
    const __bf16* __restrict__ qlat, const __bf16* __restrict__ ckv,
    const __bf16* __restrict__ wqu, const __bf16* __restrict__ wku,
    const __bf16* __restrict__ wvu, __bf16* __restrict__ qf,
    __bf16* __restrict__ kf, __bf16* __restrict__ vt) {
  __shared__ __align__(16) __bf16 As[8192];
  __shared__ __align__(16) __bf16 Bs[8192];
  int bid = (int)blockIdx.x;
  if (bid < 512) {
    gemm_body<0>(As, Bs, qlat, wqu, qf, nullptr, 1536, 1024, 2048, 2048, 1024,
                 0.12752039360437355f, bid & 31, bid >> 5, 0);
  } else if (bid < 1024) {
    bid -= 512;
    gemm_body<0>(As, Bs, ckv, wku, kf, nullptr, 1536, 512, 2048, 2048, 512,
                 1.0f, bid & 31, bid >> 5, 0);
  } else {
    bid -= 1024;
    gemm_body<0>(As, Bs, wvu, ckv, vt, nullptr, 512, 1536, 4096, 4096, 512,
                 1.0f, bid & 15, bid >> 4, 1);
  }
}

// ---------------- causal flash attention (in-block split-KV, R12) --------
// Block = 512 thr = 2 wave-quads; quad q processes KV tiles
// [q*(qt+1), (q+1)*(qt+1)) -- equal trips, one barrier/tile. Speculative
// exp with OLD running base (defer-max algebra); rescale AFTER PV (rare).
// End: quad1 dumps (O,m,l) to dead LDS; quad0 merges exactly (fp32).
__global__ __launch_bounds__(512, 1) void mla_attn(
    const __bf16* __restrict__ Qf, const __bf16* __restrict__ Kf,
    const __bf16* __restrict__ Vt, __bf16* __restrict__ ctx) {
  __shared__ __align__(16) __bf16 SM[2][32768];  // per quad: K dbuf | V dbuf
  __shared__ float MLm[128], MLl[128];

  const int bid = (int)blockIdx.x;
  const int qt = 15 - (bid >> 5);    // big first (LPT); bid%8=bh%8 (XCD)
  const int bh = bid & 31;
  const int h = bh >> 1, b = bh & 1;
  const int tid = threadIdx.x;
  const int half = tid >> 8;          // quad index
  const int htid = tid & 255;
  const int wid4 = htid >> 6;         // wave within quad
  const int lane = tid & 63;
  const int l31 = lane & 31;
  const bool hh = (lane & 32) != 0;

  __bf16* Ks = &SM[half][0];          // [2][64*128], swz (row&15)
  __bf16* Vs = &SM[half][16384];      // [2][128*64], swz (row&7)

  const __bf16* Kbh = Kf + (size_t)b * 2048 * 2048 + h * 128;
  const __bf16* Vbh = Vt + (size_t)h * 128 * 4096 + b * 2048;

  auto stage = [&](int k0, int buf) {
#pragma unroll
    for (int i = 0; i < 4; i++) {
      int e = i * 2048 + htid * 8;
      int krow = e >> 7;
      int kcol = (e & 127) ^ (8 * (krow & 15));
      async16(Kbh + (size_t)(k0 + krow) * 2048 + kcol,
              Ks + buf * 8192 + i * 2048 + wid4 * 512);
    }
#pragma unroll
    for (int i = 0; i < 4; i++) {
      int e = i * 2048 + htid * 8;
      int vrow = e >> 6;
      int vcol = (e & 63) ^ (8 * (vrow & 7));
      async16(Vbh + (size_t)vrow * 4096 + k0 + vcol,
              Vs + buf * 8192 + i * 2048 + wid4 * 512);
    }
  };

  const int q0 = qt * 128;
  const int ntile = qt + 1;           // tiles per quad
  const int kbase = half * ntile;     // this quad's first kv tile
  const int q = q0 + wid4 * 32 + l31; // this lane's q-row

  // Q fragments (B-operand layout: col=q=lane&31, k-rows (lane>>5)*8+j)
  bf16x8 qb[8];
  const __bf16* qrow =
      Qf + (size_t)(b * 2048 + q) * 2048 + h * 128 + (hh ? 8 : 0);
#pragma unroll
  for (int ds = 0; ds < 8; ds++) qb[ds] = *(const bf16x8*)(qrow + ds * 16);

  f32x16 o[4] = {};
  float mrow = 0.f, lsum = 0.f;  // finite init: speculative exp stays in range

  int cur = 0;
  stage(kbase * 64, 0);

  for (int t = 0; t < ntile; t++) {
    const int kb = kbase + t;
    const int k0 = kb * 64;
    __syncthreads();  // buf[cur] staged (all quads same trip count)
    if (t + 1 < ntile) stage(k0 + 64, cur ^ 1);

    // S^T = K Q^T : 4 independent chains (kt x dh-half), merged at the end.
    f32x16 sa[2] = {}, sb[2] = {};
    __builtin_amdgcn_s_setprio(1);
#pragma unroll
    for (int ds = 0; ds < 4; ds++) {
#pragma unroll
      for (int kt = 0; kt < 2; kt++) {
        int row = kt * 32 + l31;
        int col = (ds * 16 + (hh ? 8 : 0)) ^ (8 * (row & 15));
        bf16x8 kfr = *(const bf16x8*)(Ks + cur * 8192 + row * 128 + col);
        sa[kt] = mfma32(kfr, qb[ds], sa[kt]);
      }
    }
#pragma unroll
    for (int ds = 4; ds < 8; ds++) {
#pragma unroll
      for (int kt = 0; kt < 2; kt++) {
        int row = kt * 32 + l31;
        int col = (ds * 16 + (hh ? 8 : 0)) ^ (8 * (row & 15));
        bf16x8 kfr = *(const bf16x8*)(Ks + cur * 8192 + row * 128 + col);
        sb[kt] = mfma32(kfr, qb[ds], sb[kt]);
      }
    }
    __builtin_amdgcn_s_setprio(0);
    f32x16 sacc[2];
    sacc[0] = sa[0] + sb[0];
    sacc[1] = sa[1] + sb[1];

    // causal mask (global kb) -- true (unpermuted) key indices
    if (kb >= 2 * qt) {
#pragma unroll
      for (int kt = 0; kt < 2; kt++)
#pragma unroll
        for (int r = 0; r < 16; r++) {
          int key = k0 + kt * 32 + (r & 3) + 8 * (r >> 2) + (hh ? 4 : 0);
          if (key > q) sacc[kt][r] = -1e30f;
        }
    }

    // side-chain: block max (pairwise tree) -- NOT on the exp/PV path
    float t16[16];
#pragma unroll
    for (int r = 0; r < 16; r++) t16[r] = fmaxf(sacc[0][r], sacc[1][r]);
#pragma unroll
    for (int s = 8; s; s >>= 1)
#pragma unroll
      for (int r = 0; r < s; r++) t16[r] = fmaxf(t16[r], t16[r + s]);
    float pm = fmaxf(t16[0], __shfl_xor(t16[0], 32));

    // critical path: speculative exp with OLD base (defer-max algebra)
    float ps0 = 0.f, ps1 = 0.f, ps2 = 0.f, ps3 = 0.f;
#pragma unroll
    for (int kt = 0; kt < 2; kt++)
#pragma unroll
      for (int r = 0; r < 16; r += 4) {
        float a0 = __builtin_amdgcn_exp2f(sacc[kt][r + 0] - mrow);
        float a1 = __builtin_amdgcn_exp2f(sacc[kt][r + 1] - mrow);
        float a2 = __builtin_amdgcn_exp2f(sacc[kt][r + 2] - mrow);
        float a3 = __builtin_amdgcn_exp2f(sacc[kt][r + 3] - mrow);
        sacc[kt][r + 0] = a0; sacc[kt][r + 1] = a1;
        sacc[kt][r + 2] = a2; sacc[kt][r + 3] = a3;
        ps0 += a0; ps1 += a1; ps2 += a2; ps3 += a3;
      }

    // O += P V : A-fragment = DIRECT pack of sacc (V key-permuted).
    __builtin_amdgcn_s_setprio(1);
#pragma unroll
    for (int s = 0; s < 4; s++) {
      const int kt = s >> 1, r8 = (s & 1) * 8;
      u32x4 wv;
      wv.x = pk(sacc[kt][r8 + 0], sacc[kt][r8 + 1]);
      wv.y = pk(sacc[kt][r8 + 2], sacc[kt][r8 + 3]);
      wv.z = pk(sacc[kt][r8 + 4], sacc[kt][r8 + 5]);
      wv.w = pk(sacc[kt][r8 + 6], sacc[kt][r8 + 7]);
      bf16x8 pa = __builtin_bit_cast(bf16x8, wv);
#pragma unroll
      for (int dt = 0; dt < 4; dt++) {
        int vrow = dt * 32 + l31;
        int vcol = (s * 16 + (hh ? 8 : 0)) ^ (8 * (vrow & 7));
        bf16x8 vf = *(const bf16x8*)(Vs + cur * 8192 + vrow * 64 + vcol);
        o[dt] = mfma32(pa, vf, o[dt]);
      }
    }
    __builtin_amdgcn_s_setprio(0);

    float ps = (ps0 + ps1) + (ps2 + ps3);
    ps += __shfl_xor(ps, 32);
    lsum += ps;

    // deferred rescale AFTER PV (rare): keeps the O/l invariant exactly.
    if (__any(pm > mrow + 8.f)) {
      float mn = fmaxf(mrow, pm);
      float sf = __builtin_amdgcn_exp2f(mrow - mn);
      mrow = mn;
      lsum *= sf;
#pragma unroll
      for (int r = 0; r < 16; r++) {
        int ql = (r & 3) + 8 * (r >> 2) + (hh ? 4 : 0);
        float sr = __shfl(sf, ql);
#pragma unroll
        for (int dt = 0; dt < 4; dt++) o[dt][r] *= sr;
      }
    }
    cur ^= 1;
  }

  // ---- 2-way combine: quad1 -> LDS, quad0 merges (exact fp32) ----
  __syncthreads();  // all quads done with SM reads
  float* om = (float*)&SM[1][0];  // 16384 f32 = 64KB, [wave4][dt][lane][r]
  if (half == 1) {
#pragma unroll
    for (int dt = 0; dt < 4; dt++) {
      int base = ((wid4 * 4 + dt) * 64 + lane) * 16;
#pragma unroll
      for (int r = 0; r < 16; r++) om[base + r] = o[dt][r];
    }
    if (!hh) { MLm[wid4 * 32 + l31] = mrow; MLl[wid4 * 32 + l31] = lsum; }
  }
  __syncthreads();
  if (half == 0) {
#pragma unroll
    for (int r = 0; r < 16; r++) {
      int ql = (r & 3) + 8 * (r >> 2) + (hh ? 4 : 0);
      float m0r = __shfl(mrow, ql);
      float l0r = __shfl(lsum, ql);
      float m1r = MLm[wid4 * 32 + ql];
      float l1r = MLl[wid4 * 32 + ql];
      float M = fmaxf(m0r, m1r);
      float w0 = __builtin_amdgcn_exp2f(m0r - M);
      float w1 = __builtin_amdgcn_exp2f(m1r - M);
      float inv = 1.f / (l0r * w0 + l1r * w1);
      size_t rowi = (size_t)(b * 2048 + q0 + wid4 * 32 + ql) * 2048 + h * 128;
#pragma unroll
      for (int dt = 0; dt < 4; dt++) {
        float o1v = om[((wid4 * 4 + dt) * 64 + lane) * 16 + r];
        ctx[rowi + dt * 32 + l31] = (__bf16)((o[dt][r] * w0 + o1v * w1) * inv);
      }
    }
  }
}

// ---------------- launch ----------------
extern "C" void kernel_launch(void* const* d_in, const int* in_sizes, int n_in,
                              void* d_out, int out_size, void* d_ws, size_t ws_size,
                              hipStream_t stream) {
  (void)in_sizes; (void)n_in; (void)out_size; (void)ws_size;
  const float* x    = (const float*)d_in[0];
  const float* wqd  = (const float*)d_in[1];
  const float* wkvd = (const float*)d_in[2];
  const float* wqup = (const float*)d_in[3];
  const float* wkup = (const float*)d_in[4];
  const float* wvup = (const float*)d_in[5];
  const float* wo   = (const float*)d_in[6];
  const float* bo   = (const float*)d_in[7];

  char* ws = (char*)d_ws;
  const size_t MB = 1024 * 1024;
  __bf16* x_bf     = (__bf16*)(ws + 0);        // 16MB; reused as ctx
  __bf16* q_full   = (__bf16*)(ws + 16 * MB);  // 16MB
  __bf16* k_full   = (__bf16*)(ws + 32 * MB);  // 16MB
  __bf16* vt       = (__bf16*)(ws + 48 * MB);  // 16MB (key axis pi-permuted)
  __bf16* qkv_lat  = (__bf16*)(ws + 64 * MB);  // 12MB [4096,1536]; reused wo_bf
  __bf16* wqkvd_bf = (__bf16*)(ws + 76 * MB);  // 6MB  [1536,2048] fused
  __bf16* wqup_bf  = (__bf16*)(ws + 82 * MB);  // 4MB
  __bf16* wkup_bf  = (__bf16*)(ws + 86 * MB);  // 2MB
  __bf16* wvup_bf  = (__bf16*)(ws + 88 * MB);  // 2MB -> total 90MB
  __bf16* ctx   = x_bf;      // x_bf dead after fused down-proj
  __bf16* wo_bf = qkv_lat;   // qkv_lat dead after gemm_mid

  // one launch: x + all five projection weights
  cvt_all<<<15360, 256, 0, stream>>>(x, wqd, wkvd, wqup, wkup, wvup, x_bf,
                                     wqkvd_bf, wqup_bf, wkup_bf, wvup_bf);

  dim3 blk(256);
  // [Q_lat | C_kv] = x @ [Wq_down; Wkv_down]^T   (fused, N=1536)
  gemm_bt<0><<<dim3(32, 12), blk, 0, stream>>>(x_bf, wqkvd_bf, qkv_lat, nullptr,
                                               2048, 2048, 1536, 1536, 2048, 1.0f);
  // Q-up + K-up + V^T-up in ONE launch (1536 blocks, 3/CU)
  gemm_mid<<<1536, blk, 0, stream>>>(qkv_lat, qkv_lat + 1024, wqup_bf, wkup_bf,
                                     wvup_bf, q_full, k_full, vt);
  cvt_bf16<<<4096, 256, 0, stream>>>(wo, wo_bf);  // qkv_lat free after mid
  // ctx = causal_attention(Q, K, V): 512 blocks x 512 thr, split-KV in-block
  mla_attn<<<512, 512, 0, stream>>>(q_full, k_full, vt, ctx);
  // out = ctx @ Wo^T + bo  (fp32)
  gemm_bt<1><<<dim3(32, 16), blk, 0, stream>>>(ctx, wo_bf, (float*)d_out, bo,
                                               2048, 2048, 2048, 2048, 2048, 1.0f);
}